// Round 1
// baseline (566.746 us; speedup 1.0000x reference)
//
#include <hip/hip_runtime.h>

typedef __attribute__((ext_vector_type(4))) float f32x4;
typedef __attribute__((ext_vector_type(8))) short s16x8;

#define NR 512      // rows of x / out
#define KD 512      // inner dim
#define CC 100000   // columns of weight / out
#define BN 64       // cols per block
#define LDSK 40     // padded k-stride in LDS shorts (80B rows: 16B-aligned b128 reads)
#define NSTG 16     // K stages of 32

static __device__ __forceinline__ unsigned short f2bf(float f) {
    union { float f; unsigned u; } v; v.f = f;
    unsigned r = v.u + 0x7FFFu + ((v.u >> 16) & 1u);  // round-to-nearest-even
    return (unsigned short)(r >> 16);
}

// Kernel 1: per-row L2 norm of x + convert x to bf16 (bit pattern in ushort)
__global__ __launch_bounds__(256) void prep_kernel(const float* __restrict__ x,
                                                   float* __restrict__ xn,
                                                   unsigned short* __restrict__ xb) {
    const int row = blockIdx.x;
    const int t = threadIdx.x;
    const float* xr = x + row * KD;
    float v0 = xr[t];
    float v1 = xr[t + 256];
    float ss = v0 * v0 + v1 * v1;
    #pragma unroll
    for (int off = 32; off > 0; off >>= 1) ss += __shfl_down(ss, off, 64);
    __shared__ float sred[4];
    if ((t & 63) == 0) sred[t >> 6] = ss;
    __syncthreads();
    if (t == 0) xn[row] = sqrtf(sred[0] + sred[1] + sred[2] + sred[3]);
    xb[row * KD + t]       = f2bf(v0);
    xb[row * KD + t + 256] = f2bf(v1);
}

// convert an 8-float K-column slice to bf16, accumulate column sumsq, stage to LDS
#define CONVERT_STAGE(BUF, S)                                                        \
  do {                                                                               \
    ss += S[0]*S[0] + S[1]*S[1] + S[2]*S[2] + S[3]*S[3]                              \
        + S[4]*S[4] + S[5]*S[5] + S[6]*S[6] + S[7]*S[7];                             \
    ushort4 p0_, p1_;                                                                \
    p0_.x = f2bf(S[0]); p0_.y = f2bf(S[1]); p0_.z = f2bf(S[2]); p0_.w = f2bf(S[3]);  \
    p1_.x = f2bf(S[4]); p1_.y = f2bf(S[5]); p1_.z = f2bf(S[6]); p1_.w = f2bf(S[7]);  \
    *(ushort4*)&ldsB[BUF][cL * LDSK + kg * 8]     = p0_;                             \
    *(ushort4*)&ldsB[BUF][cL * LDSK + kg * 8 + 4] = p1_;                             \
  } while (0)

// Kernel 2: out[m, c] = clamp( (x·w_c)/||w_c||, -||x_m||, +||x_m|| )
// Block: 256 threads (4 waves), 64-col stripe, 256-row half (blockIdx&1).
// Single raw s_barrier per K-stage, LDS double-buffer, depth-4 global B pipeline
// (vmcnt never drained at the barrier -> loads stay in flight across stages).
__global__ __launch_bounds__(256, 3) void gemm_kernel(const float* __restrict__ w,
                                                      const unsigned short* __restrict__ xb,
                                                      const float* __restrict__ xn,
                                                      float* __restrict__ out) {
    __shared__ __align__(16) unsigned short ldsB[2][BN * LDSK];
    __shared__ float sPart[4][BN];
    __shared__ float sInv[BN];

    const int t    = threadIdx.x;
    const int lane = t & 63;
    const int wv   = t >> 6;          // wave 0..3
    const int ci   = blockIdx.x >> 1; // col tile 0..1562
    const int half = blockIdx.x & 1;  // row half
    const int c0   = ci * BN;

    const int cL = lane;              // staging: col 0..63
    const int kg = wv;                // staging: k-group 0..3 (8 k-rows each)
    int cg = c0 + cL;
    if (cg > CC - 1) cg = CC - 1;     // clamp partial last tile (dup loads, unused)
    const float* wcol = w + cg;

    const int rowbase = half * 256 + wv * 64;
    const int arow = lane & 15;       // A: m within 16-tile
    const int akq  = lane >> 4;       // A: k-quad
    const unsigned short* abase = xb + (size_t)(rowbase + arow) * KD + akq * 8;

    f32x4 acc[4][4];
    #pragma unroll
    for (int i = 0; i < 4; ++i)
        #pragma unroll
        for (int j = 0; j < 4; ++j)
            acc[i][j] = {0.f, 0.f, 0.f, 0.f};

    float ss = 0.f;

    // ---- prologue: stages 0..3 issued, stage 0 converted into buf0 ----
    float s0[8], b0[8], b1[8], b2[8];
    #pragma unroll
    for (int r = 0; r < 8; ++r) s0[r] = wcol[(size_t)(kg * 8 + r) * CC];
    s16x8 af[4];
    #pragma unroll
    for (int rt = 0; rt < 4; ++rt) af[rt] = *(const s16x8*)(abase + rt * 16 * KD);
    #pragma unroll
    for (int r = 0; r < 8; ++r) b0[r] = wcol[(size_t)(32 + kg * 8 + r) * CC];
    #pragma unroll
    for (int r = 0; r < 8; ++r) b1[r] = wcol[(size_t)(64 + kg * 8 + r) * CC];
    #pragma unroll
    for (int r = 0; r < 8; ++r) b2[r] = wcol[(size_t)(96 + kg * 8 + r) * CC];

    CONVERT_STAGE(0, s0);
    asm volatile("s_waitcnt lgkmcnt(0)" ::: "memory");
    __builtin_amdgcn_s_barrier();

    #pragma unroll
    for (int i = 0; i < NSTG; ++i) {
        // 1. B fragments from buf[i&1] (written last stage, fenced by barrier)
        s16x8 bf[4];
        #pragma unroll
        for (int ct = 0; ct < 4; ++ct)
            bf[ct] = *(const s16x8*)&ldsB[i & 1][(ct * 16 + arow) * LDSK + akq * 8];

        // 2. issue stage i+4 global loads (depth-4: ~3 iters of latency slack)
        float bn[8];
        if (i + 4 < NSTG) {
            #pragma unroll
            for (int r = 0; r < 8; ++r)
                bn[r] = wcol[(size_t)((i + 4) * 32 + kg * 8 + r) * CC];
        } else {
            #pragma unroll
            for (int r = 0; r < 8; ++r) bn[r] = 0.f;
        }

        // 3. issue next iter's A fragments (L2-resident xb)
        s16x8 afn[4];
        if (i + 1 < NSTG) {
            #pragma unroll
            for (int rt = 0; rt < 4; ++rt)
                afn[rt] = *(const s16x8*)(abase + rt * 16 * KD + (i + 1) * 32);
        } else {
            #pragma unroll
            for (int rt = 0; rt < 4; ++rt) afn[rt] = af[rt];
        }

        // 4. convert stage i+1 (loaded 3 iters ago; counted vmcnt wait only)
        if (i + 1 < NSTG) {
            CONVERT_STAGE((i + 1) & 1, b0);
        }

        // 5. fence LDS ops only -- global loads stay in flight across the barrier
        asm volatile("s_waitcnt lgkmcnt(0)" ::: "memory");
        __builtin_amdgcn_s_barrier();

        // 6. MFMA cluster
        __builtin_amdgcn_s_setprio(1);
        #pragma unroll
        for (int rt = 0; rt < 4; ++rt)
            #pragma unroll
            for (int ct = 0; ct < 4; ++ct)
                acc[rt][ct] = __builtin_amdgcn_mfma_f32_16x16x32_bf16(af[rt], bf[ct], acc[rt][ct], 0, 0, 0);
        __builtin_amdgcn_s_setprio(0);

        // 7. rotate pipeline registers (full unroll -> pure SSA renaming)
        #pragma unroll
        for (int r = 0; r < 8; ++r) { b0[r] = b1[r]; b1[r] = b2[r]; b2[r] = bn[r]; }
        #pragma unroll
        for (int rt = 0; rt < 4; ++rt) af[rt] = afn[rt];
    }

    // column inverse norms: 4 partials per column
    sPart[kg][cL] = ss;
    __syncthreads();
    if (t < BN) {
        const float tot = sPart[0][t] + sPart[1][t] + sPart[2][t] + sPart[3][t];
        sInv[t] = 1.0f / sqrtf(tot);
    }
    __syncthreads();

    // epilogue: clamp(acc*inv, -xn, +xn) == clip(cos)*||x||   (no div chain)
    // C/D layout: col=lane&15, row=(lane>>4)*4+reg
    #pragma unroll
    for (int rt = 0; rt < 4; ++rt) {
        const int rbase = rowbase + rt * 16 + akq * 4;
        const f32x4 xnv = *(const f32x4*)(xn + rbase);
        #pragma unroll
        for (int ct = 0; ct < 4; ++ct) {
            const int col = c0 + ct * 16 + arow;
            if (col < CC) {
                const float inv = sInv[ct * 16 + arow];
                float* op = out + (size_t)rbase * CC + col;
                #pragma unroll
                for (int r = 0; r < 4; ++r) {
                    float cv = acc[rt][ct][r] * inv;
                    const float xr = xnv[r];
                    cv = fminf(xr, fmaxf(-xr, cv));
                    __builtin_nontemporal_store(cv, op + (size_t)r * CC);
                }
            }
        }
    }
}

// Kernel 3: per-row target fixup (AngleLinear margin term), 512 rows
__global__ __launch_bounds__(512) void fixup_kernel(const int* __restrict__ target,
                                                    const float* __restrict__ xn,
                                                    float* __restrict__ out) {
    const int i = threadIdx.x;
    const int tg = target[i];
    const float xni = xn[i];
    float* p = out + (size_t)i * CC + tg;
    const float val = *p;
    float c = val / xni;
    c = fminf(1.0f, fmaxf(-1.0f, c));
    const float c2 = c * c;
    const float cosm = 8.0f * c2 * c2 - 8.0f * c2 + 1.0f;
    const float theta = acosf(c);
    const float kf = floorf(4.0f * theta / 3.141592653f);
    const float sign = (((int)kf) & 1) ? -1.0f : 1.0f;
    const float phi = sign * cosm - 2.0f * kf;
    const float lam = 1500.0f / 1.1f;  // max(5, 1500/(1+0.1*1))
    const float add = (phi - c) * xni / (1.0f + lam);
    *p = val + add;
}

extern "C" void kernel_launch(void* const* d_in, const int* in_sizes, int n_in,
                              void* d_out, int out_size, void* d_ws, size_t ws_size,
                              hipStream_t stream) {
    const float* x      = (const float*)d_in[0];
    const int*   target = (const int*)d_in[1];
    const float* w      = (const float*)d_in[2];
    float* out = (float*)d_out;

    float* xn = (float*)d_ws;                                        // 512 f32
    unsigned short* xb = (unsigned short*)((char*)d_ws + 2048);      // 512x512 bf16

    prep_kernel<<<NR, 256, 0, stream>>>(x, xn, xb);
    const int nblk = ((CC + BN - 1) / BN) * 2;                       // 1563 col tiles x 2 row halves
    gemm_kernel<<<nblk, 256, 0, stream>>>(w, xb, xn, out);
    fixup_kernel<<<1, 512, 0, stream>>>(target, xn, out);
}

// Round 2
// 521.158 us; speedup vs baseline: 1.0875x; 1.0875x over previous
//
#include <hip/hip_runtime.h>

typedef __attribute__((ext_vector_type(4))) float f32x4;
typedef __attribute__((ext_vector_type(8))) short s16x8;

#define NR 512      // rows of x / out
#define KD 512      // inner dim
#define CC 100000   // columns of weight / out
#define BN 32       // cols per block (100000/32 = 3125 exact)
#define LDSK 40     // padded k-stride in LDS shorts (80B rows: 16B-aligned b128 reads)
#define NSTG 16     // K stages of 32

static __device__ __forceinline__ unsigned short f2bf(float f) {
    union { float f; unsigned u; } v; v.f = f;
    unsigned r = v.u + 0x7FFFu + ((v.u >> 16) & 1u);  // round-to-nearest-even
    return (unsigned short)(r >> 16);
}

// Kernel 1: per-row L2 norm of x + convert x to bf16 (bit pattern in ushort)
__global__ __launch_bounds__(256) void prep_kernel(const float* __restrict__ x,
                                                   float* __restrict__ xn,
                                                   unsigned short* __restrict__ xb) {
    const int row = blockIdx.x;
    const int t = threadIdx.x;
    const float* xr = x + row * KD;
    float v0 = xr[t];
    float v1 = xr[t + 256];
    float ss = v0 * v0 + v1 * v1;
    #pragma unroll
    for (int off = 32; off > 0; off >>= 1) ss += __shfl_down(ss, off, 64);
    __shared__ float sred[4];
    if ((t & 63) == 0) sred[t >> 6] = ss;
    __syncthreads();
    if (t == 0) xn[row] = sqrtf(sred[0] + sred[1] + sred[2] + sred[3]);
    xb[row * KD + t]       = f2bf(v0);
    xb[row * KD + t + 256] = f2bf(v1);
}

// convert a 4-float K-column slice to bf16, accumulate column sumsq, stage to LDS
#define CONVERT_STAGE(BUF, S)                                                        \
  do {                                                                               \
    ss += S[0]*S[0] + S[1]*S[1] + S[2]*S[2] + S[3]*S[3];                             \
    ushort4 pk_;                                                                     \
    pk_.x = f2bf(S[0]); pk_.y = f2bf(S[1]); pk_.z = f2bf(S[2]); pk_.w = f2bf(S[3]);  \
    *(ushort4*)&ldsB[BUF][cL * LDSK + kq * 4] = pk_;                                 \
  } while (0)

// Kernel 2: out[m, c] = clamp( (x·w_c)/||w_c||, -||x_m||, +||x_m|| )
// Block: 256 threads (4 waves), 32-col stripe, FULL 512 rows (W read once).
// Single raw s_barrier per K-stage, LDS double-buffer, depth-4 global B pipeline
// (vmcnt never drained in the loop -> loads stay in flight across barriers).
__global__ __launch_bounds__(256, 3) void gemm_kernel(const float* __restrict__ w,
                                                      const unsigned short* __restrict__ xb,
                                                      const float* __restrict__ xn,
                                                      float* __restrict__ out) {
    __shared__ __align__(16) unsigned short ldsB[2][BN * LDSK];
    __shared__ float sPart[8][BN];
    __shared__ float sInv[BN];

    const int t    = threadIdx.x;
    const int lane = t & 63;
    const int wv   = t >> 6;          // wave 0..3
    const int c0   = blockIdx.x * BN; // global col base (exact tiling)

    const int cL = t & 31;            // staging: col 0..31
    const int kq = t >> 5;            // staging: k-quad 0..7 (k = kq*4..kq*4+3)
    const float* wcol = w + c0 + cL;

    const int rowbase = wv * 128;
    const int arow = lane & 15;       // A: m within 16-tile
    const int akq  = lane >> 4;       // A: k-quad
    const unsigned short* abase = xb + (size_t)(rowbase + arow) * KD + akq * 8;

    f32x4 acc[8][2];
    #pragma unroll
    for (int i = 0; i < 8; ++i) {
        acc[i][0] = {0.f, 0.f, 0.f, 0.f};
        acc[i][1] = {0.f, 0.f, 0.f, 0.f};
    }

    float ss = 0.f;

    // ---- prologue: stages 0..3 issued, stage 0 converted into buf0 ----
    float s0[4], b0[4], b1[4], b2[4];
    #pragma unroll
    for (int r = 0; r < 4; ++r) s0[r] = wcol[(size_t)(kq * 4 + r) * CC];
    #pragma unroll
    for (int r = 0; r < 4; ++r) b0[r] = wcol[(size_t)(32 + kq * 4 + r) * CC];
    #pragma unroll
    for (int r = 0; r < 4; ++r) b1[r] = wcol[(size_t)(64 + kq * 4 + r) * CC];
    #pragma unroll
    for (int r = 0; r < 4; ++r) b2[r] = wcol[(size_t)(96 + kq * 4 + r) * CC];

    CONVERT_STAGE(0, s0);
    asm volatile("s_waitcnt lgkmcnt(0)" ::: "memory");
    __builtin_amdgcn_s_barrier();

    #pragma unroll
    for (int i = 0; i < NSTG; ++i) {
        // 1. A fragments for this iter, issued first (L2-resident xb; consumed last)
        s16x8 af[8];
        #pragma unroll
        for (int rt = 0; rt < 8; ++rt)
            af[rt] = *(const s16x8*)(abase + rt * 16 * KD + i * 32);

        // 2. B fragments from buf[i&1] (written last stage, fenced by barrier)
        const s16x8 bf0 = *(const s16x8*)&ldsB[i & 1][arow * LDSK + akq * 8];
        const s16x8 bf1 = *(const s16x8*)&ldsB[i & 1][(16 + arow) * LDSK + akq * 8];

        // 3. issue stage i+4 global loads (depth-4: ~3 iters of latency slack)
        float bn[4];
        if (i + 4 < NSTG) {
            #pragma unroll
            for (int r = 0; r < 4; ++r)
                bn[r] = wcol[(size_t)((i + 4) * 32 + kq * 4 + r) * CC];
        } else {
            #pragma unroll
            for (int r = 0; r < 4; ++r) bn[r] = 0.f;
        }

        // 4. convert stage i+1 (loaded 3 iters ago; counted vmcnt wait only)
        if (i + 1 < NSTG) {
            CONVERT_STAGE((i + 1) & 1, b0);
        }

        // 5. fence LDS ops only -- global loads stay in flight across the barrier
        asm volatile("s_waitcnt lgkmcnt(0)" ::: "memory");
        __builtin_amdgcn_s_barrier();

        // 6. MFMA cluster
        __builtin_amdgcn_s_setprio(1);
        #pragma unroll
        for (int rt = 0; rt < 8; ++rt) {
            acc[rt][0] = __builtin_amdgcn_mfma_f32_16x16x32_bf16(af[rt], bf0, acc[rt][0], 0, 0, 0);
            acc[rt][1] = __builtin_amdgcn_mfma_f32_16x16x32_bf16(af[rt], bf1, acc[rt][1], 0, 0, 0);
        }
        __builtin_amdgcn_s_setprio(0);

        // 7. rotate pipeline registers (full unroll -> pure SSA renaming)
        #pragma unroll
        for (int r = 0; r < 4; ++r) { b0[r] = b1[r]; b1[r] = b2[r]; b2[r] = bn[r]; }
    }

    // column inverse norms: 8 partials per column
    sPart[kq][cL] = ss;
    __syncthreads();
    if (t < BN) {
        float tot = 0.f;
        #pragma unroll
        for (int i = 0; i < 8; ++i) tot += sPart[i][t];
        sInv[t] = 1.0f / sqrtf(tot);
    }
    __syncthreads();

    // epilogue: clamp(acc*inv, -xn, +xn) == clip(cos)*||x||   (no div chain)
    // C/D layout: col=lane&15, row=(lane>>4)*4+reg.  Plain stores: L2 merges the
    // two 16-col ct segments into full 128B lines (WRITE_SIZE exact, no nt).
    #pragma unroll
    for (int rt = 0; rt < 8; ++rt) {
        const int rbase = rowbase + rt * 16 + akq * 4;
        const f32x4 xnv = *(const f32x4*)(xn + rbase);
        #pragma unroll
        for (int ct = 0; ct < 2; ++ct) {
            const float inv = sInv[ct * 16 + arow];
            float* op = out + (size_t)rbase * CC + c0 + ct * 16 + arow;
            #pragma unroll
            for (int r = 0; r < 4; ++r) {
                float cv = acc[rt][ct][r] * inv;
                const float xr = xnv[r];
                cv = fminf(xr, fmaxf(-xr, cv));
                op[(size_t)r * CC] = cv;
            }
        }
    }
}

// Kernel 3: per-row target fixup (AngleLinear margin term), 512 rows
__global__ __launch_bounds__(512) void fixup_kernel(const int* __restrict__ target,
                                                    const float* __restrict__ xn,
                                                    float* __restrict__ out) {
    const int i = threadIdx.x;
    const int tg = target[i];
    const float xni = xn[i];
    float* p = out + (size_t)i * CC + tg;
    const float val = *p;
    float c = val / xni;
    c = fminf(1.0f, fmaxf(-1.0f, c));
    const float c2 = c * c;
    const float cosm = 8.0f * c2 * c2 - 8.0f * c2 + 1.0f;
    const float theta = acosf(c);
    const float kf = floorf(4.0f * theta / 3.141592653f);
    const float sign = (((int)kf) & 1) ? -1.0f : 1.0f;
    const float phi = sign * cosm - 2.0f * kf;
    const float lam = 1500.0f / 1.1f;  // max(5, 1500/(1+0.1*1))
    const float add = (phi - c) * xni / (1.0f + lam);
    *p = val + add;
}

extern "C" void kernel_launch(void* const* d_in, const int* in_sizes, int n_in,
                              void* d_out, int out_size, void* d_ws, size_t ws_size,
                              hipStream_t stream) {
    const float* x      = (const float*)d_in[0];
    const int*   target = (const int*)d_in[1];
    const float* w      = (const float*)d_in[2];
    float* out = (float*)d_out;

    float* xn = (float*)d_ws;                                        // 512 f32
    unsigned short* xb = (unsigned short*)((char*)d_ws + 2048);      // 512x512 bf16

    prep_kernel<<<NR, 256, 0, stream>>>(x, xn, xb);
    gemm_kernel<<<CC / BN, 256, 0, stream>>>(w, xb, xn, out);
    fixup_kernel<<<1, 512, 0, stream>>>(target, xn, out);
}